// Round 3
// baseline (269.175 us; speedup 1.0000x reference)
//
#include <hip/hip_runtime.h>

#define Bn 128
#define Vn 128000
#define SLICES 8
#define SLICE_LEN 16000      // Vn/SLICES
#define TPB 256
#define WTPB 512
#define NB1 512              // L1 bins: K>>21 (e<=1 -> bin<=508)
#define NB2 512              // sub-bins: K bits [20:12]
#define CAP 512              // cut-sub gather cap
#define CAPB 4096            // bin-level candidate cap per (row,query)
#define FMINV -3.4028234663852886e38f
#define FOUT  -3.3895313892515355e38f
#define FIXS 268435456.0     // 2^28
#define FIXI (1.0/268435456.0)
#define SUMMASK ((1ULL<<45)-1)

// ---- ws arena (bytes) ----
#define OFF_ROWS   0u
#define OFF_SLICEM 65536u
#define OFF_L1P    81920u                 // u64 packed [Bn][NB1] = 512KB
#define OFF_LCNT   606208u                // u32 [Bn][8]
#define ZERO_BEG   81920u
#define ZERO_BYTES 528384u                // [OFF_L1P, OFF_LCNT+4KB)
#define OFF_LISTS  610304u                // u64 [Bn][4][CAPB] = 16MB
#define OFF_Q4BIG  17387520u              // u64 [Bn][CAPB] = 4MB
// total need ~21.6MB (ws observed = 256MiB via harness fills)

// Unnormalized e = exp2((v-M)/T*log2e) <= 1. All decisions scale-invariant.
// L1 histogram is u64 fixed point: [count:19 | round(sum*2^28):45] -> integer
// atomics are order-exact => deterministic, and 1 atomic/elem instead of 2.
struct RowWS {
  double Zd;
  float S2f, t4;
  unsigned thrBits;
  int q4mode, token;
  unsigned v0; int i0; unsigned v2; int i2;
  unsigned cutBin[5];                 // q0..3 cut bin (collectB), q4 (resolve2)
  unsigned CbefB[4]; double SbefB[4]; // bin-level exclusive suffix above cut
  double Sbef4;                       // q4: sum strictly above cut bin
};

__device__ inline void dec(unsigned long long p, double& s, unsigned& c){
  c = (unsigned)(p >> 45);
  s = (double)(p & SUMMASK) * FIXI;
}

// wave-aggregated list append: 1 global atomic per wave per call
__device__ inline void wappend(bool pred, unsigned long long e,
                               unsigned* cnt, unsigned long long* dst, unsigned cap){
  unsigned long long mask = __ballot(pred);
  if (!mask) return;
  int lane = threadIdx.x & 63;
  int leader = __builtin_ctzll(mask);
  unsigned base = 0;
  if (lane == leader) base = atomicAdd(cnt, (unsigned)__popcll(mask));
  base = __shfl(base, leader);
  if (pred){
    unsigned pos = base + (unsigned)__popcll(mask & ((1ULL << lane) - 1ULL));
    if (pos < cap) dst[pos] = e;
  }
}

// 256-thread suffix-inclusive scan over 512 (s,c); thread t owns 2t,2t+1.
__device__ inline void sufscan512(int tid, double s0, unsigned c0, double s1, unsigned c1,
    double& S0i, unsigned& C0i, double& S1i, unsigned& C1i, double& St,
    double* wT, unsigned* wTc){
  __syncthreads();
  int lane = tid & 63, wv = tid >> 6;
  double vS = s0 + s1; unsigned vC = c0 + c1;
  #pragma unroll
  for (int off = 1; off < 64; off <<= 1){
    double tS = __shfl_down(vS, off); unsigned tC = __shfl_down(vC, off);
    if (lane + off < 64){ vS += tS; vC += tC; }
  }
  if (lane == 0){ wT[wv] = vS; wTc[wv] = vC; }
  __syncthreads();
  double add = 0.0; unsigned addc = 0u;
  for (int w = wv + 1; w < 4; ++w){ add += wT[w]; addc += wTc[w]; }
  S0i = vS + add; C0i = vC + addc;
  S1i = S0i - s0; C1i = C0i - c0;
  St = wT[0] + wT[1] + wT[2] + wT[3];
}

// ---- pass 1: per-slice max ----
__global__ __launch_bounds__(TPB) void k_max(const float* __restrict__ logits, float* sliceM){
  __shared__ float sF[TPB/64];
  int blk = blockIdx.x, b = blk >> 3, sl = blk & 7, tid = threadIdx.x;
  const float4* l4 = (const float4*)(logits + (size_t)b*Vn + sl*SLICE_LEN);
  float m = -3.4e38f;
  for (int j = tid; j < SLICE_LEN/4; j += TPB){
    float4 v = l4[j];
    m = fmaxf(m, fmaxf(fmaxf(v.x, v.y), fmaxf(v.z, v.w)));
  }
  #pragma unroll
  for (int o = 32; o; o >>= 1) m = fmaxf(m, __shfl_down(m, o));
  if ((tid & 63) == 0) sF[tid >> 6] = m;
  __syncthreads();
  if (tid == 0){
    float mm = sF[0];
    for (int w = 1; w < TPB/64; ++w) mm = fmaxf(mm, sF[w]);
    sliceM[b*SLICES + sl] = mm;
  }
}

// ---- pass 2: e = exp2((v-M)*c1), cache K, packed-u64 L1 histogram ----
__global__ __launch_bounds__(TPB) void k_l1hist(const float* __restrict__ logits,
    const float* __restrict__ temps, const float* __restrict__ sliceM,
    unsigned long long* L1P, unsigned* __restrict__ Kc){
  __shared__ unsigned long long hP[4*NB1];
  __shared__ float sM;
  int blk = blockIdx.x, b = blk >> 3, sl = blk & 7, tid = threadIdx.x;
  int cp = (tid >> 6) & 3;
  for (int i = tid; i < 4*NB1; i += TPB) hP[i] = 0ull;
  float T = temps[b];
  float c1 = 1.4426950408889634f / T;
  if (tid == 0){
    float M = sliceM[b*SLICES];
    for (int s = 1; s < SLICES; ++s) M = fmaxf(M, sliceM[b*SLICES + s]);
    sM = M;
  }
  __syncthreads();
  float M = sM;
  size_t base = (size_t)b*Vn + sl*SLICE_LEN;
  const float4* l4 = (const float4*)(logits + base);
  uint4* K4 = (uint4*)(Kc + base);
  for (int j = tid; j < SLICE_LEN/4; j += TPB){
    float4 v = l4[j];
    uint4 kk;
    float p0 = exp2f((v.x - M)*c1); kk.x = __float_as_uint(p0);
    float p1 = exp2f((v.y - M)*c1); kk.y = __float_as_uint(p1);
    float p2 = exp2f((v.z - M)*c1); kk.z = __float_as_uint(p2);
    float p3 = exp2f((v.w - M)*c1); kk.w = __float_as_uint(p3);
    unsigned b0 = min(kk.x >> 21, NB1-1u), b1 = min(kk.y >> 21, NB1-1u);
    unsigned b2 = min(kk.z >> 21, NB1-1u), b3 = min(kk.w >> 21, NB1-1u);
    unsigned long long f0 = (unsigned long long)((double)p0 * FIXS + 0.5) + (1ULL<<45);
    unsigned long long f1 = (unsigned long long)((double)p1 * FIXS + 0.5) + (1ULL<<45);
    unsigned long long f2 = (unsigned long long)((double)p2 * FIXS + 0.5) + (1ULL<<45);
    unsigned long long f3 = (unsigned long long)((double)p3 * FIXS + 0.5) + (1ULL<<45);
    atomicAdd(&hP[cp*NB1 + b0], f0);
    atomicAdd(&hP[cp*NB1 + b1], f1);
    atomicAdd(&hP[cp*NB1 + b2], f2);
    atomicAdd(&hP[cp*NB1 + b3], f3);
    K4[j] = kk;
  }
  __syncthreads();
  for (int bin = tid; bin < NB1; bin += TPB){
    unsigned long long c = hP[bin] + hP[NB1+bin] + hP[2*NB1+bin] + hP[3*NB1+bin];
    if (c) atomicAdd(&L1P[(size_t)b*NB1 + bin], c);
  }
}

// ---- pass 3: embedded L1 walk + bin-level candidate collect (q0..q3) ----
__global__ __launch_bounds__(TPB) void k_collectB(const unsigned* __restrict__ Kc,
    const unsigned long long* __restrict__ L1P, RowWS* rows,
    const int* __restrict__ top_ks, const float* __restrict__ top_ps,
    const float* __restrict__ top_ps2, const float* __restrict__ min_ps,
    unsigned long long* lists, unsigned* lcnt){
  __shared__ double wT[4]; __shared__ unsigned wTc[4];
  __shared__ int mx0, mx1, mx2, mnz;
  __shared__ unsigned sCut[4];
  int blk = blockIdx.x, b = blk >> 3, sl = blk & 7, tid = threadIdx.x;
  RowWS& R = rows[b];
  if (tid == 0){ mx0 = -1; mx1 = -1; mx2 = -1; mnz = NB1; }
  int B0 = 2*tid, B1 = 2*tid+1;
  double s0, s1; unsigned c0, c1;
  dec(L1P[(size_t)b*NB1 + B0], s0, c0);
  dec(L1P[(size_t)b*NB1 + B1], s1, c1);
  double S0i, S1i, St; unsigned C0i, C1i;
  sufscan512(tid, s0, c0, s1, c1, S0i, C0i, S1i, C1i, St, wT, wTc);
  float minp = min_ps[b];
  unsigned thrBits = __float_as_uint(minp);
  int thrBin = (int)(thrBits >> 21); if (thrBin > NB1-1) thrBin = NB1-1;
  unsigned k = (unsigned)top_ks[b];
  double tZ1 = (double)top_ps[b] * St, tZ2 = (double)top_ps2[b] * St;
  if (c0){ if (C0i >= k) atomicMax(&mx0,B0); if (S0i > tZ1) atomicMax(&mx1,B0); if (S0i > tZ2) atomicMax(&mx2,B0); atomicMin(&mnz,B0); }
  if (c1){ if (C1i >= k) atomicMax(&mx0,B1); if (S1i > tZ1) atomicMax(&mx1,B1); if (S1i > tZ2) atomicMax(&mx2,B1); atomicMin(&mnz,B1); }
  __syncthreads();
  int w0 = mx0;
  int w1 = (mx1 >= 0) ? mx1 : mnz;
  int w2 = (mx2 >= 0) ? mx2 : mnz;
  if (tid == 0){
    sCut[0]=(unsigned)w0; sCut[1]=(unsigned)w1; sCut[2]=(unsigned)w2; sCut[3]=(unsigned)thrBin;
    if (sl == 0){
      R.thrBits = thrBits; R.Zd = St;
      R.cutBin[0]=(unsigned)w0; R.cutBin[1]=(unsigned)w1; R.cutBin[2]=(unsigned)w2; R.cutBin[3]=(unsigned)thrBin;
    }
  }
  if (sl == 0){
    #define PUB(qi, wq) { if (B0==(wq)){ R.CbefB[qi]=C0i-c0; R.SbefB[qi]=S0i-s0; } else if (B1==(wq)){ R.CbefB[qi]=C1i-c1; R.SbefB[qi]=S1i-s1; } }
    PUB(0, w0) PUB(1, w1) PUB(2, w2) PUB(3, thrBin)
    #undef PUB
  }
  __syncthreads();
  unsigned tb0 = sCut[0], tb1 = sCut[1], tb2 = sCut[2], tb3 = sCut[3];
  int base = sl*SLICE_LEN;
  const uint4* K4 = (const uint4*)(Kc + (size_t)b*Vn + base);
  unsigned long long* Lb = lists + (size_t)b*4*CAPB;
  unsigned* lc = &lcnt[b*8];
  for (int j = tid; j < SLICE_LEN/4; j += TPB){
    uint4 kk = K4[j];
    #pragma unroll
    for (int c = 0; c < 4; ++c){
      unsigned K = (c==0)?kk.x:(c==1)?kk.y:(c==2)?kk.z:kk.w;
      unsigned bin = K >> 21;
      bool p0 = (bin == tb0), p1 = (bin == tb1), p2 = (bin == tb2), p3 = (bin == tb3);
      if (__ballot(p0 | p1 | p2 | p3)){
        unsigned long long e = (((unsigned long long)(~K)) << 32) | (unsigned)(base + j*4 + c);
        wappend(p0, e, lc+0, Lb + 0*CAPB, CAPB);
        wappend(p1, e, lc+1, Lb + 1*CAPB, CAPB);
        wappend(p2, e, lc+2, Lb + 2*CAPB, CAPB);
        wappend(p3, e, lc+3, Lb + 3*CAPB, CAPB);
      }
    }
  }
}

// ---- pass 4: per-row resolve (sub-hist per query from lists) + q4 L1 walk ----
__global__ __launch_bounds__(WTPB) void k_resolve2(RowWS* rows,
    const unsigned long long* __restrict__ lists, const unsigned* __restrict__ lcnt,
    const unsigned long long* __restrict__ L1P,
    const int* __restrict__ top_ks, const float* __restrict__ top_ps,
    const float* __restrict__ top_ps2, const float* __restrict__ uarr){
  __shared__ double   sS[NB2+1];
  __shared__ unsigned sC[NB2+1];
  __shared__ double   hS[NB2];
  __shared__ unsigned hC[NB2];
  __shared__ unsigned long long Ls[CAP];
  __shared__ int mx, mnz, gcnt;
  __shared__ double sSexc; __shared__ unsigned sCexc;
  __shared__ unsigned shVS[4]; __shared__ int shIS[4]; __shared__ double shSK[4];
  __shared__ double sT4d;
  int b = blockIdx.x, t = threadIdx.x;
  RowWS& R = rows[b];
  unsigned thrBits = R.thrBits; double Zd = R.Zd;
  int k = top_ks[b];
  double tauP = (double)top_ps[b] * Zd, tauP2 = (double)top_ps2[b] * Zd;
  for (int q = 0; q < 4; ++q){
    hS[t] = 0.0; hC[t] = 0u;
    if (t == 0){ mx = -1; mnz = NB2; gcnt = 0; sS[NB2] = 0.0; sC[NB2] = 0u; }
    __syncthreads();
    int n = (int)lcnt[b*8+q]; if (n > CAPB) n = CAPB;
    const unsigned long long* L = lists + ((size_t)b*4 + q)*CAPB;
    for (int j = t; j < n; j += WTPB){
      unsigned K = ~(unsigned)(L[j] >> 32);
      unsigned sub = (K >> 12) & (NB2-1);
      unsafeAtomicAdd(&hS[sub], (double)__uint_as_float(K));
      atomicAdd(&hC[sub], 1u);
    }
    __syncthreads();
    sS[t] = hS[t]; sC[t] = hC[t];
    __syncthreads();
    for (int off = 1; off < NB2; off <<= 1){
      double   vs = sS[t] + ((t+off < NB2) ? sS[t+off] : 0.0);
      unsigned vc = sC[t] + ((t+off < NB2) ? sC[t+off] : 0u);
      __syncthreads();
      sS[t] = vs; sC[t] = vc;
      __syncthreads();
    }
    unsigned baseC = R.CbefB[q]; double baseS = R.SbefB[q];
    int w;
    if (q == 3){
      w = (int)((thrBits >> 12) & (NB2-1));
    } else {
      unsigned c = hC[t];
      if (c){
        if (q == 0){ if (baseC + sC[t] >= (unsigned)k) atomicMax(&mx, t); }
        else { double tau = (q == 1) ? tauP : tauP2; if (baseS + sS[t] > tau) atomicMax(&mx, t); }
        atomicMin(&mnz, t);
      }
      __syncthreads();
      w = (mx >= 0) ? mx : mnz;     // lists q0..q2 are non-empty by construction
    }
    if (t == w){ sSexc = baseS + sS[w+1]; sCexc = baseC + sC[w+1]; }
    for (int j = t; j < n; j += WTPB){
      unsigned long long e = L[j];
      unsigned K = ~(unsigned)(e >> 32);
      if (((K >> 12) & (NB2-1)) == (unsigned)w){
        int p = atomicAdd(&gcnt, 1);
        if (p < CAP) Ls[p] = e;
      }
    }
    __syncthreads();
    if (t == 0){
      int m = gcnt; if (m > CAP) m = CAP;
      for (int i2 = 1; i2 < m; ++i2){
        unsigned long long key = Ls[i2]; int j = i2-1;
        while (j >= 0 && Ls[j] > key){ Ls[j+1] = Ls[j]; --j; }
        Ls[j+1] = key;
      }
      double S = sSexc;
      if (q == 0){
        if (m > 0){
          int mm = k - (int)sCexc; if (mm < 1) mm = 1; if (mm > m) mm = m;
          for (int j = 0; j < mm; ++j){ unsigned K = ~(unsigned)(Ls[j] >> 32); S += (double)__uint_as_float(K); }
          unsigned long long e = Ls[mm-1];
          shVS[0] = ~(unsigned)(e >> 32); shIS[0] = (int)(unsigned)(e & 0xFFFFFFFFu); shSK[0] = S;
        } else { shVS[0] = 0u; shIS[0] = 0x7FFFFFFF; shSK[0] = S; }
      } else if (q < 3){
        double tau = (q == 1) ? tauP : tauP2;
        int last = -1;
        for (int j = 0; j < m; ++j){
          if (S > tau) break;
          unsigned K = ~(unsigned)(Ls[j] >> 32);
          S += (double)__uint_as_float(K); last = j;
        }
        if (m > 0){
          int pick = (last < 0) ? 0 : last;
          unsigned long long e = Ls[pick];
          shVS[q] = ~(unsigned)(e >> 32); shIS[q] = (int)(unsigned)(e & 0xFFFFFFFFu); shSK[q] = S;
        } else { shVS[q] = 0u; shIS[q] = 0x7FFFFFFF; shSK[q] = S; }
      } else {
        for (int j = 0; j < m; ++j){
          unsigned K = ~(unsigned)(Ls[j] >> 32);
          if (K < thrBits) break;
          S += (double)__uint_as_float(K);
        }
        shVS[3] = thrBits; shIS[3] = 0x7FFFFFFF; shSK[3] = S;
      }
    }
    __syncthreads();
  }
  // combine + q4 L1 walk
  if (t == 0){
    unsigned v0 = shVS[0]; int i0 = shIS[0]; double tot = shSK[0];
    if (shVS[1] > v0 || (shVS[1] == v0 && shIS[1] < i0)){ v0 = shVS[1]; i0 = shIS[1]; tot = shSK[1]; }
    if (shVS[3] > v0 || (shVS[3] == v0 && shIS[3] < i0)){ v0 = shVS[3]; i0 = shIS[3]; tot = shSK[3]; }
    R.v0 = v0; R.i0 = i0;
    R.v2 = shVS[2]; R.i2 = shIS[2]; R.S2f = (float)shSK[2];
    float t4 = uarr[b] * (float)tot;
    R.t4 = t4;
    sT4d = (double)t4;
    mx = -1;
    sS[NB1] = 0.0; sC[NB1] = 0u;
  }
  double s; unsigned c;
  dec(L1P[(size_t)b*NB1 + t], s, c);
  __syncthreads();
  sS[t] = s; sC[t] = c;
  __syncthreads();
  for (int off = 1; off < NB1; off <<= 1){
    double   vs = sS[t] + ((t+off < NB1) ? sS[t+off] : 0.0);
    unsigned vc = sC[t] + ((t+off < NB1) ? sC[t+off] : 0u);
    __syncthreads();
    sS[t] = vs; sC[t] = vc;
    __syncthreads();
  }
  double t4d = sT4d;
  if (c && sS[t] >= t4d) atomicMax(&mx, t);
  __syncthreads();
  int w = mx;
  if (w < 0){
    if (t == 0){ R.q4mode = 2; R.token = R.i0; }
  } else {
    if (t == 0) R.q4mode = 0;
    if (t == w){ R.cutBin[4] = (unsigned)w; R.Sbef4 = sS[t+1]; }
  }
}

// ---- pass 5: logprob write (in-place over Kc) + bin-level q4 collect ----
__global__ __launch_bounds__(TPB) void k_out2(const RowWS* __restrict__ rows,
    unsigned long long* q4big, unsigned* lcnt, float* __restrict__ outLp){
  int blk = blockIdx.x, b = blk >> 3, sl = blk & 7, tid = threadIdx.x;
  unsigned v2 = rows[b].v2; int i2 = rows[b].i2; float S2f = rows[b].S2f;
  float lgS2 = logf(S2f);
  bool doColl = (rows[b].q4mode == 0);
  unsigned tb4 = rows[b].cutBin[4];
  int base = sl*SLICE_LEN;
  float4* O4 = (float4*)(outLp + (size_t)b*Vn + base);
  const uint4* K4 = (const uint4*)O4;   // aliased: read K, write logprob
  unsigned long long* dst = q4big + (size_t)b*CAPB;
  unsigned* lc = &lcnt[b*8+4];
  for (int j = tid; j < SLICE_LEN/4; j += TPB){
    uint4 kk = K4[j];
    float4 o;
    #pragma unroll
    for (int c = 0; c < 4; ++c){
      unsigned K = (c==0)?kk.x:(c==1)?kk.y:(c==2)?kk.z:kk.w;
      int i = base + j*4 + c;
      bool pr = doColl && ((K >> 21) == tb4);
      wappend(pr, (((unsigned long long)(~K)) << 32) | (unsigned)i, lc, dst, CAPB);
      float p = __uint_as_float(K);
      float val = (K > v2 || (K == v2 && i <= i2)) ? fmaxf(logf(p) - lgS2, FMINV) : FOUT;
      if (c==0) o.x = val; else if (c==1) o.y = val; else if (c==2) o.z = val; else o.w = val;
    }
    O4[j] = o;
  }
}

// ---- pass 6: q4 sub-hist from bin list, scan, filter, pick token ----
__global__ __launch_bounds__(WTPB) void k_pick2(RowWS* rows, const unsigned long long* q4big,
    const unsigned* lcnt, float* __restrict__ outTok, float* __restrict__ outNtlp){
  __shared__ double   hS[NB2];
  __shared__ unsigned hC[NB2];
  __shared__ double wT[8];
  __shared__ int mx, mnz, mcnt;
  __shared__ double sSbS;
  __shared__ unsigned long long Ls[CAP];
  int b = blockIdx.x, t = threadIdx.x;
  RowWS& R = rows[b];
  int token = -1; unsigned pB = 0u;
  if (R.q4mode == 2){
    if (t) return;
    token = R.token; pB = R.v0;
  } else {
    int n = (int)lcnt[b*8+4]; if (n > CAPB) n = CAPB;
    hS[t] = 0.0; hC[t] = 0u;
    if (t == 0){ mx = -1; mnz = NB2; mcnt = 0; }
    __syncthreads();
    for (int j = t; j < n; j += WTPB){
      unsigned K = ~(unsigned)(q4big[(size_t)b*CAPB + j] >> 32);
      unsigned sub = (K >> 12) & (NB2-1);
      unsafeAtomicAdd(&hS[sub], (double)__uint_as_float(K));
      atomicAdd(&hC[sub], 1u);
    }
    __syncthreads();
    double s = hS[t]; unsigned c = hC[t];
    int lane = t & 63, wv = t >> 6;
    double vS = s;
    #pragma unroll
    for (int off = 1; off < 64; off <<= 1){
      double tS = __shfl_down(vS, off);
      if (lane + off < 64) vS += tS;
    }
    if (lane == 0) wT[wv] = vS;
    __syncthreads();
    double add = 0.0;
    for (int w2 = wv + 1; w2 < 8; ++w2) add += wT[w2];
    double Si = vS + add;
    double baseS = R.Sbef4, t4d = (double)R.t4;
    if (c){
      if (baseS + Si >= t4d) atomicMax(&mx, t);
      atomicMin(&mnz, t);
    }
    __syncthreads();
    int w = (mx >= 0) ? mx : ((mnz < NB2) ? mnz : -1);
    if (w < 0){
      if (t) return;
      token = R.i0; pB = R.v0;
    } else {
      if (t == w) sSbS = baseS + (Si - s);
      __syncthreads();
      for (int j = t; j < n; j += WTPB){
        unsigned long long e = q4big[(size_t)b*CAPB + j];
        unsigned K = ~(unsigned)(e >> 32);
        if (((K >> 12) & (NB2-1)) == (unsigned)w){
          int p = atomicAdd(&mcnt, 1);
          if (p < CAP) Ls[p] = e;
        }
      }
      __syncthreads();
      if (t) return;
      int m = mcnt; if (m > CAP) m = CAP;
      for (int i2 = 1; i2 < m; ++i2){
        unsigned long long key = Ls[i2]; int j = i2-1;
        while (j >= 0 && Ls[j] > key){ Ls[j+1] = Ls[j]; --j; }
        Ls[j+1] = key;
      }
      double S = sSbS, t4dd = (double)R.t4;
      unsigned v0 = R.v0; int i0 = R.i0;
      token = -1; pB = R.v0;
      for (int j = 0; j < m; ++j){
        unsigned K = ~(unsigned)(Ls[j] >> 32);
        int idx = (int)(unsigned)(Ls[j] & 0xFFFFFFFFu);
        bool kept = (K > v0) || (K == v0 && idx <= i0);
        if (!kept){ token = i0; pB = v0; break; }
        S += (double)__uint_as_float(K);
        if (S >= t4dd){ token = idx; pB = K; break; }
      }
      if (token < 0){ token = i0; pB = v0; }
    }
  }
  unsigned v2 = R.v2; int i2 = R.i2;
  bool kept2 = (pB > v2) || (pB == v2 && token <= i2);
  float pt = __uint_as_float(pB);
  float lp = kept2 ? fmaxf(logf(pt) - logf(R.S2f), FMINV) : FOUT;
  outTok[b] = (float)token;
  outNtlp[b] = lp;
}

extern "C" void kernel_launch(void* const* d_in, const int* in_sizes, int n_in,
                              void* d_out, int out_size, void* d_ws, size_t ws_size,
                              hipStream_t stream)
{
  const float* logits  = (const float*)d_in[0];
  const float* temps   = (const float*)d_in[1];
  const int*   top_ks  = (const int*)d_in[2];
  const float* top_ps  = (const float*)d_in[3];
  const float* top_ps2 = (const float*)d_in[4];
  const float* min_ps  = (const float*)d_in[5];
  const float* uarr    = (const float*)d_in[6];

  char* ws = (char*)d_ws;
  RowWS*    rows   = (RowWS*)(ws + OFF_ROWS);
  float*    sliceM = (float*)(ws + OFF_SLICEM);
  unsigned long long* L1P   = (unsigned long long*)(ws + OFF_L1P);
  unsigned* lcnt   = (unsigned*)(ws + OFF_LCNT);
  unsigned long long* lists = (unsigned long long*)(ws + OFF_LISTS);
  unsigned long long* q4big = (unsigned long long*)(ws + OFF_Q4BIG);

  float* outTok  = (float*)d_out;
  float* outLp   = outTok + Bn;
  float* outNtlp = outLp + (size_t)Bn * Vn;
  unsigned* Kc   = (unsigned*)outLp;     // K-cache lives in the big output buffer

  const int G = Bn * SLICES;
  hipMemsetAsync(ws + ZERO_BEG, 0, ZERO_BYTES, stream);
  k_max      <<<G,  TPB,  0, stream>>>(logits, sliceM);
  k_l1hist   <<<G,  TPB,  0, stream>>>(logits, temps, sliceM, L1P, Kc);
  k_collectB <<<G,  TPB,  0, stream>>>(Kc, L1P, rows, top_ks, top_ps, top_ps2, min_ps, lists, lcnt);
  k_resolve2 <<<Bn, WTPB, 0, stream>>>(rows, lists, lcnt, L1P, top_ks, top_ps, top_ps2, uarr);
  k_out2     <<<G,  TPB,  0, stream>>>(rows, q4big, lcnt, outLp);
  k_pick2    <<<Bn, WTPB, 0, stream>>>(rows, q4big, lcnt, outTok, outNtlp);
}

// Round 4
// 213.332 us; speedup vs baseline: 1.2618x; 1.2618x over previous
//
#include <hip/hip_runtime.h>

#define Bn 128
#define Vn 128000
#define SLICES 8
#define SLICE_LEN 16000      // Vn/SLICES
#define TPB 256
#define WTPB 512
#define NB1 512              // L1 bins: K>>21 (e<=1 -> bin<=508)
#define NB2 512              // sub-bins: K bits [20:12]
#define CAP 512              // cut-sub gather cap
#define CAPM 16384           // merged bin-level candidate cap per row
#define CAPB 4096            // q4 bin-level candidate cap per row
#define LCAP 3072            // per-block LDS staging cap (24KB)
#define FMINV -3.4028234663852886e38f
#define FOUT  -3.3895313892515355e38f
#define FIXS 268435456.0     // 2^28
#define FIXI (1.0/268435456.0)
#define SUMMASK ((1ULL<<45)-1)

// ---- ws arena (bytes) ----
#define OFF_ROWS   0u
#define OFF_SLICEM 65536u
#define OFF_L1P    81920u                 // u64 packed [Bn][NB1] = 512KB
#define OFF_LCNT   606208u                // u32 [Bn][8]
#define ZERO_BEG   81920u
#define ZERO_BYTES 528384u                // [OFF_L1P, OFF_LCNT+4KB)
#define OFF_LISTS  610304u                // u64 [Bn][CAPM] = 16MB (merged)
#define OFF_Q4BIG  17387520u              // u64 [Bn][CAPB] = 4MB

// Unnormalized e = exp2((v-M)/T*log2e) <= 1. All decisions scale-invariant.
// L1 histogram u64 fixed point: [count:19 | round(sum*2^28):45] -> integer
// atomics are order-exact => deterministic, 1 atomic/elem.
struct RowWS {
  double Zd;
  float S2f, t4;
  unsigned thrBits;
  int q4mode, token;
  unsigned v0; int i0; unsigned v2; int i2;
  unsigned cutBin[5];                 // q0..3 cut bin (collectB), q4 (resolve2)
  unsigned CbefB[4]; double SbefB[4]; // bin-level exclusive suffix above cut
  double Sbef4;                       // q4: sum strictly above cut bin
};

__device__ inline void dec(unsigned long long p, double& s, unsigned& c){
  c = (unsigned)(p >> 45);
  s = (double)(p & SUMMASK) * FIXI;
}

// wave-aggregated global append (used only on rare LDS-overflow spill + q4)
__device__ inline void wappend(bool pred, unsigned long long e,
                               unsigned* cnt, unsigned long long* dst, unsigned cap){
  unsigned long long mask = __ballot(pred);
  if (!mask) return;
  int lane = threadIdx.x & 63;
  int leader = __builtin_ctzll(mask);
  unsigned base = 0;
  if (lane == leader) base = atomicAdd(cnt, (unsigned)__popcll(mask));
  base = __shfl(base, leader);
  if (pred){
    unsigned pos = base + (unsigned)__popcll(mask & ((1ULL << lane) - 1ULL));
    if (pos < cap) dst[pos] = e;
  }
}

// 256-thread suffix-inclusive scan over 512 (s,c); thread t owns 2t,2t+1.
__device__ inline void sufscan512(int tid, double s0, unsigned c0, double s1, unsigned c1,
    double& S0i, unsigned& C0i, double& S1i, unsigned& C1i, double& St,
    double* wT, unsigned* wTc){
  __syncthreads();
  int lane = tid & 63, wv = tid >> 6;
  double vS = s0 + s1; unsigned vC = c0 + c1;
  #pragma unroll
  for (int off = 1; off < 64; off <<= 1){
    double tS = __shfl_down(vS, off); unsigned tC = __shfl_down(vC, off);
    if (lane + off < 64){ vS += tS; vC += tC; }
  }
  if (lane == 0){ wT[wv] = vS; wTc[wv] = vC; }
  __syncthreads();
  double add = 0.0; unsigned addc = 0u;
  for (int w = wv + 1; w < 4; ++w){ add += wT[w]; addc += wTc[w]; }
  S0i = vS + add; C0i = vC + addc;
  S1i = S0i - s0; C1i = C0i - c0;
  St = wT[0] + wT[1] + wT[2] + wT[3];
}

// ---- pass 1: per-slice max ----
__global__ __launch_bounds__(TPB) void k_max(const float* __restrict__ logits, float* sliceM){
  __shared__ float sF[TPB/64];
  int blk = blockIdx.x, b = blk >> 3, sl = blk & 7, tid = threadIdx.x;
  const float4* l4 = (const float4*)(logits + (size_t)b*Vn + sl*SLICE_LEN);
  float m = -3.4e38f;
  for (int j = tid; j < SLICE_LEN/4; j += TPB){
    float4 v = l4[j];
    m = fmaxf(m, fmaxf(fmaxf(v.x, v.y), fmaxf(v.z, v.w)));
  }
  #pragma unroll
  for (int o = 32; o; o >>= 1) m = fmaxf(m, __shfl_down(m, o));
  if ((tid & 63) == 0) sF[tid >> 6] = m;
  __syncthreads();
  if (tid == 0){
    float mm = sF[0];
    for (int w = 1; w < TPB/64; ++w) mm = fmaxf(mm, sF[w]);
    sliceM[b*SLICES + sl] = mm;
  }
}

// ---- pass 2: e = exp2((v-M)*c1), cache K, packed-u64 L1 histogram ----
__global__ __launch_bounds__(TPB) void k_l1hist(const float* __restrict__ logits,
    const float* __restrict__ temps, const float* __restrict__ sliceM,
    unsigned long long* L1P, unsigned* __restrict__ Kc){
  __shared__ unsigned long long hP[4*NB1];
  __shared__ float sM;
  int blk = blockIdx.x, b = blk >> 3, sl = blk & 7, tid = threadIdx.x;
  int cp = (tid >> 6) & 3;
  for (int i = tid; i < 4*NB1; i += TPB) hP[i] = 0ull;
  float T = temps[b];
  float c1 = 1.4426950408889634f / T;
  if (tid == 0){
    float M = sliceM[b*SLICES];
    for (int s = 1; s < SLICES; ++s) M = fmaxf(M, sliceM[b*SLICES + s]);
    sM = M;
  }
  __syncthreads();
  float M = sM;
  size_t base = (size_t)b*Vn + sl*SLICE_LEN;
  const float4* l4 = (const float4*)(logits + base);
  uint4* K4 = (uint4*)(Kc + base);
  for (int j = tid; j < SLICE_LEN/4; j += TPB){
    float4 v = l4[j];
    uint4 kk;
    float p0 = exp2f((v.x - M)*c1); kk.x = __float_as_uint(p0);
    float p1 = exp2f((v.y - M)*c1); kk.y = __float_as_uint(p1);
    float p2 = exp2f((v.z - M)*c1); kk.z = __float_as_uint(p2);
    float p3 = exp2f((v.w - M)*c1); kk.w = __float_as_uint(p3);
    unsigned b0 = min(kk.x >> 21, NB1-1u), b1 = min(kk.y >> 21, NB1-1u);
    unsigned b2 = min(kk.z >> 21, NB1-1u), b3 = min(kk.w >> 21, NB1-1u);
    unsigned long long f0 = (unsigned long long)((double)p0 * FIXS + 0.5) + (1ULL<<45);
    unsigned long long f1 = (unsigned long long)((double)p1 * FIXS + 0.5) + (1ULL<<45);
    unsigned long long f2 = (unsigned long long)((double)p2 * FIXS + 0.5) + (1ULL<<45);
    unsigned long long f3 = (unsigned long long)((double)p3 * FIXS + 0.5) + (1ULL<<45);
    atomicAdd(&hP[cp*NB1 + b0], f0);
    atomicAdd(&hP[cp*NB1 + b1], f1);
    atomicAdd(&hP[cp*NB1 + b2], f2);
    atomicAdd(&hP[cp*NB1 + b3], f3);
    K4[j] = kk;
  }
  __syncthreads();
  for (int bin = tid; bin < NB1; bin += TPB){
    unsigned long long c = hP[bin] + hP[NB1+bin] + hP[2*NB1+bin] + hP[3*NB1+bin];
    if (c) atomicAdd(&L1P[(size_t)b*NB1 + bin], c);
  }
}

// ---- pass 3: embedded L1 walk + MERGED bin-level collect (LDS-staged) ----
__global__ __launch_bounds__(TPB) void k_collectB(const unsigned* __restrict__ Kc,
    const unsigned long long* __restrict__ L1P, RowWS* rows,
    const int* __restrict__ top_ks, const float* __restrict__ top_ps,
    const float* __restrict__ top_ps2, const float* __restrict__ min_ps,
    unsigned long long* lists, unsigned* lcnt){
  __shared__ double wT[4]; __shared__ unsigned wTc[4];
  __shared__ int mx0, mx1, mx2, mnz;
  __shared__ unsigned sCut[4];
  __shared__ unsigned long long Lbuf[LCAP];
  __shared__ unsigned lCnt, gBase;
  int blk = blockIdx.x, b = blk >> 3, sl = blk & 7, tid = threadIdx.x;
  RowWS& R = rows[b];
  if (tid == 0){ mx0 = -1; mx1 = -1; mx2 = -1; mnz = NB1; lCnt = 0u; }
  int B0 = 2*tid, B1 = 2*tid+1;
  double s0, s1; unsigned c0, c1;
  dec(L1P[(size_t)b*NB1 + B0], s0, c0);
  dec(L1P[(size_t)b*NB1 + B1], s1, c1);
  double S0i, S1i, St; unsigned C0i, C1i;
  sufscan512(tid, s0, c0, s1, c1, S0i, C0i, S1i, C1i, St, wT, wTc);
  float minp = min_ps[b];
  unsigned thrBits = __float_as_uint(minp);
  int thrBin = (int)(thrBits >> 21); if (thrBin > NB1-1) thrBin = NB1-1;
  unsigned k = (unsigned)top_ks[b];
  double tZ1 = (double)top_ps[b] * St, tZ2 = (double)top_ps2[b] * St;
  if (c0){ if (C0i >= k) atomicMax(&mx0,B0); if (S0i > tZ1) atomicMax(&mx1,B0); if (S0i > tZ2) atomicMax(&mx2,B0); atomicMin(&mnz,B0); }
  if (c1){ if (C1i >= k) atomicMax(&mx0,B1); if (S1i > tZ1) atomicMax(&mx1,B1); if (S1i > tZ2) atomicMax(&mx2,B1); atomicMin(&mnz,B1); }
  __syncthreads();
  int w0 = mx0;
  int w1 = (mx1 >= 0) ? mx1 : mnz;
  int w2 = (mx2 >= 0) ? mx2 : mnz;
  if (tid == 0){
    sCut[0]=(unsigned)w0; sCut[1]=(unsigned)w1; sCut[2]=(unsigned)w2; sCut[3]=(unsigned)thrBin;
    if (sl == 0){
      R.thrBits = thrBits; R.Zd = St;
      R.cutBin[0]=(unsigned)w0; R.cutBin[1]=(unsigned)w1; R.cutBin[2]=(unsigned)w2; R.cutBin[3]=(unsigned)thrBin;
    }
  }
  if (sl == 0){
    #define PUB(qi, wq) { if (B0==(wq)){ R.CbefB[qi]=C0i-c0; R.SbefB[qi]=S0i-s0; } else if (B1==(wq)){ R.CbefB[qi]=C1i-c1; R.SbefB[qi]=S1i-s1; } }
    PUB(0, w0) PUB(1, w1) PUB(2, w2) PUB(3, thrBin)
    #undef PUB
  }
  __syncthreads();
  unsigned tb0 = sCut[0], tb1 = sCut[1], tb2 = sCut[2], tb3 = sCut[3];
  int base = sl*SLICE_LEN;
  const uint4* K4 = (const uint4*)(Kc + (size_t)b*Vn + base);
  unsigned long long* dst = lists + (size_t)b*CAPM;
  unsigned* gc = &lcnt[b*8+0];
  for (int j = tid; j < SLICE_LEN/4; j += TPB){
    uint4 kk = K4[j];
    #pragma unroll
    for (int c = 0; c < 4; ++c){
      unsigned K = (c==0)?kk.x:(c==1)?kk.y:(c==2)?kk.z:kk.w;
      unsigned bin = K >> 21;
      bool pr = (bin == tb0) | (bin == tb1) | (bin == tb2) | (bin == tb3);
      if (pr){
        unsigned long long e = (((unsigned long long)(~K)) << 32) | (unsigned)(base + j*4 + c);
        unsigned pos = atomicAdd(&lCnt, 1u);
        if (pos < LCAP) Lbuf[pos] = e;
        else { unsigned gp = atomicAdd(gc, 1u); if (gp < CAPM) dst[gp] = e; }
      }
    }
  }
  __syncthreads();
  unsigned cnt = lCnt; if (cnt > LCAP) cnt = LCAP;
  if (tid == 0) gBase = atomicAdd(gc, cnt);
  __syncthreads();
  unsigned gb = gBase;
  for (unsigned i = tid; i < cnt; i += TPB){
    unsigned p = gb + i;
    if (p < CAPM) dst[p] = Lbuf[i];
  }
}

// ---- pass 4: per-row resolve from merged list + q4 L1 walk ----
__global__ __launch_bounds__(WTPB) void k_resolve2(RowWS* rows,
    const unsigned long long* __restrict__ lists, const unsigned* __restrict__ lcnt,
    const unsigned long long* __restrict__ L1P,
    const int* __restrict__ top_ks, const float* __restrict__ top_ps,
    const float* __restrict__ top_ps2, const float* __restrict__ uarr){
  __shared__ double   sS[NB2+1];
  __shared__ unsigned sC[NB2+1];
  __shared__ double   hS[NB2];
  __shared__ unsigned hC[NB2];
  __shared__ unsigned long long Ls[CAP];
  __shared__ int mx, mnz, gcnt;
  __shared__ double sSexc; __shared__ unsigned sCexc;
  __shared__ unsigned shVS[4]; __shared__ int shIS[4]; __shared__ double shSK[4];
  __shared__ double sT4d;
  int b = blockIdx.x, t = threadIdx.x;
  RowWS& R = rows[b];
  unsigned thrBits = R.thrBits; double Zd = R.Zd;
  int k = top_ks[b];
  double tauP = (double)top_ps[b] * Zd, tauP2 = (double)top_ps2[b] * Zd;
  int n = (int)lcnt[b*8+0]; if (n > CAPM) n = CAPM;
  const unsigned long long* L = lists + (size_t)b*CAPM;
  for (int q = 0; q < 4; ++q){
    // dedupe: q2 == q1 when tau and cut bin coincide (block-uniform branch)
    if (q == 2 && tauP2 == tauP && R.cutBin[2] == R.cutBin[1]){
      if (t == 0){ shVS[2] = shVS[1]; shIS[2] = shIS[1]; shSK[2] = shSK[1]; }
      __syncthreads();
      continue;
    }
    hS[t] = 0.0; hC[t] = 0u;
    if (t == 0){ mx = -1; mnz = NB2; gcnt = 0; sS[NB2] = 0.0; sC[NB2] = 0u; }
    __syncthreads();
    unsigned tb = R.cutBin[q];
    for (int j = t; j < n; j += WTPB){
      unsigned K = ~(unsigned)(L[j] >> 32);
      if ((K >> 21) == tb){
        unsigned sub = (K >> 12) & (NB2-1);
        unsafeAtomicAdd(&hS[sub], (double)__uint_as_float(K));
        atomicAdd(&hC[sub], 1u);
      }
    }
    __syncthreads();
    sS[t] = hS[t]; sC[t] = hC[t];
    __syncthreads();
    for (int off = 1; off < NB2; off <<= 1){
      double   vs = sS[t] + ((t+off < NB2) ? sS[t+off] : 0.0);
      unsigned vc = sC[t] + ((t+off < NB2) ? sC[t+off] : 0u);
      __syncthreads();
      sS[t] = vs; sC[t] = vc;
      __syncthreads();
    }
    unsigned baseC = R.CbefB[q]; double baseS = R.SbefB[q];
    int w;
    if (q == 3){
      w = (int)((thrBits >> 12) & (NB2-1));
    } else {
      unsigned c = hC[t];
      if (c){
        if (q == 0){ if (baseC + sC[t] >= (unsigned)k) atomicMax(&mx, t); }
        else { double tau = (q == 1) ? tauP : tauP2; if (baseS + sS[t] > tau) atomicMax(&mx, t); }
        atomicMin(&mnz, t);
      }
      __syncthreads();
      w = (mx >= 0) ? mx : mnz;     // cut bins q0..q2 are non-empty
    }
    if (t == w){ sSexc = baseS + sS[w+1]; sCexc = baseC + sC[w+1]; }
    unsigned pre = (tb << 9) | (unsigned)w;
    for (int j = t; j < n; j += WTPB){
      unsigned long long e = L[j];
      unsigned K = ~(unsigned)(e >> 32);
      if ((K >> 12) == pre){
        int p = atomicAdd(&gcnt, 1);
        if (p < CAP) Ls[p] = e;
      }
    }
    __syncthreads();
    if (t == 0){
      int m = gcnt; if (m > CAP) m = CAP;
      for (int i2 = 1; i2 < m; ++i2){
        unsigned long long key = Ls[i2]; int j = i2-1;
        while (j >= 0 && Ls[j] > key){ Ls[j+1] = Ls[j]; --j; }
        Ls[j+1] = key;
      }
      double S = sSexc;
      if (q == 0){
        if (m > 0){
          int mm = k - (int)sCexc; if (mm < 1) mm = 1; if (mm > m) mm = m;
          for (int j = 0; j < mm; ++j){ unsigned K = ~(unsigned)(Ls[j] >> 32); S += (double)__uint_as_float(K); }
          unsigned long long e = Ls[mm-1];
          shVS[0] = ~(unsigned)(e >> 32); shIS[0] = (int)(unsigned)(e & 0xFFFFFFFFu); shSK[0] = S;
        } else { shVS[0] = 0u; shIS[0] = 0x7FFFFFFF; shSK[0] = S; }
      } else if (q < 3){
        double tau = (q == 1) ? tauP : tauP2;
        int last = -1;
        for (int j = 0; j < m; ++j){
          if (S > tau) break;
          unsigned K = ~(unsigned)(Ls[j] >> 32);
          S += (double)__uint_as_float(K); last = j;
        }
        if (m > 0){
          int pick = (last < 0) ? 0 : last;
          unsigned long long e = Ls[pick];
          shVS[q] = ~(unsigned)(e >> 32); shIS[q] = (int)(unsigned)(e & 0xFFFFFFFFu); shSK[q] = S;
        } else { shVS[q] = 0u; shIS[q] = 0x7FFFFFFF; shSK[q] = S; }
      } else {
        for (int j = 0; j < m; ++j){
          unsigned K = ~(unsigned)(Ls[j] >> 32);
          if (K < thrBits) break;
          S += (double)__uint_as_float(K);
        }
        shVS[3] = thrBits; shIS[3] = 0x7FFFFFFF; shSK[3] = S;
      }
    }
    __syncthreads();
  }
  // combine + q4 L1 walk
  if (t == 0){
    unsigned v0 = shVS[0]; int i0 = shIS[0]; double tot = shSK[0];
    if (shVS[1] > v0 || (shVS[1] == v0 && shIS[1] < i0)){ v0 = shVS[1]; i0 = shIS[1]; tot = shSK[1]; }
    if (shVS[3] > v0 || (shVS[3] == v0 && shIS[3] < i0)){ v0 = shVS[3]; i0 = shIS[3]; tot = shSK[3]; }
    R.v0 = v0; R.i0 = i0;
    R.v2 = shVS[2]; R.i2 = shIS[2]; R.S2f = (float)shSK[2];
    float t4 = uarr[b] * (float)tot;
    R.t4 = t4;
    sT4d = (double)t4;
    mx = -1;
    sS[NB1] = 0.0; sC[NB1] = 0u;
  }
  double s; unsigned c;
  dec(L1P[(size_t)b*NB1 + t], s, c);
  __syncthreads();
  sS[t] = s; sC[t] = c;
  __syncthreads();
  for (int off = 1; off < NB1; off <<= 1){
    double   vs = sS[t] + ((t+off < NB1) ? sS[t+off] : 0.0);
    unsigned vc = sC[t] + ((t+off < NB1) ? sC[t+off] : 0u);
    __syncthreads();
    sS[t] = vs; sC[t] = vc;
    __syncthreads();
  }
  double t4d = sT4d;
  if (c && sS[t] >= t4d) atomicMax(&mx, t);
  __syncthreads();
  int w = mx;
  if (w < 0){
    if (t == 0){ R.q4mode = 2; R.token = R.i0; }
  } else {
    if (t == 0) R.q4mode = 0;
    if (t == w){ R.cutBin[4] = (unsigned)w; R.Sbef4 = sS[t+1]; }
  }
}

// ---- pass 5: logprob write (in-place over Kc) + bin-level q4 collect ----
__global__ __launch_bounds__(TPB) void k_out2(const RowWS* __restrict__ rows,
    unsigned long long* q4big, unsigned* lcnt, float* __restrict__ outLp){
  int blk = blockIdx.x, b = blk >> 3, sl = blk & 7, tid = threadIdx.x;
  unsigned v2 = rows[b].v2; int i2 = rows[b].i2; float S2f = rows[b].S2f;
  float lgS2 = logf(S2f);
  bool doColl = (rows[b].q4mode == 0);
  unsigned tb4 = rows[b].cutBin[4];
  int base = sl*SLICE_LEN;
  float4* O4 = (float4*)(outLp + (size_t)b*Vn + base);
  const uint4* K4 = (const uint4*)O4;   // aliased: read K, write logprob
  unsigned long long* dst = q4big + (size_t)b*CAPB;
  unsigned* lc = &lcnt[b*8+4];
  for (int j = tid; j < SLICE_LEN/4; j += TPB){
    uint4 kk = K4[j];
    float4 o;
    #pragma unroll
    for (int c = 0; c < 4; ++c){
      unsigned K = (c==0)?kk.x:(c==1)?kk.y:(c==2)?kk.z:kk.w;
      int i = base + j*4 + c;
      bool pr = doColl && ((K >> 21) == tb4);
      wappend(pr, (((unsigned long long)(~K)) << 32) | (unsigned)i, lc, dst, CAPB);
      float p = __uint_as_float(K);
      float val = (K > v2 || (K == v2 && i <= i2)) ? fmaxf(logf(p) - lgS2, FMINV) : FOUT;
      if (c==0) o.x = val; else if (c==1) o.y = val; else if (c==2) o.z = val; else o.w = val;
    }
    O4[j] = o;
  }
}

// ---- pass 6: q4 sub-hist from bin list, scan, filter, pick token ----
__global__ __launch_bounds__(WTPB) void k_pick2(RowWS* rows, const unsigned long long* q4big,
    const unsigned* lcnt, float* __restrict__ outTok, float* __restrict__ outNtlp){
  __shared__ double   hS[NB2];
  __shared__ unsigned hC[NB2];
  __shared__ double wT[8];
  __shared__ int mx, mnz, mcnt;
  __shared__ double sSbS;
  __shared__ unsigned long long Ls[CAP];
  int b = blockIdx.x, t = threadIdx.x;
  RowWS& R = rows[b];
  int token = -1; unsigned pB = 0u;
  if (R.q4mode == 2){
    if (t) return;
    token = R.token; pB = R.v0;
  } else {
    int n = (int)lcnt[b*8+4]; if (n > CAPB) n = CAPB;
    hS[t] = 0.0; hC[t] = 0u;
    if (t == 0){ mx = -1; mnz = NB2; mcnt = 0; }
    __syncthreads();
    for (int j = t; j < n; j += WTPB){
      unsigned K = ~(unsigned)(q4big[(size_t)b*CAPB + j] >> 32);
      unsigned sub = (K >> 12) & (NB2-1);
      unsafeAtomicAdd(&hS[sub], (double)__uint_as_float(K));
      atomicAdd(&hC[sub], 1u);
    }
    __syncthreads();
    double s = hS[t]; unsigned c = hC[t];
    int lane = t & 63, wv = t >> 6;
    double vS = s;
    #pragma unroll
    for (int off = 1; off < 64; off <<= 1){
      double tS = __shfl_down(vS, off);
      if (lane + off < 64) vS += tS;
    }
    if (lane == 0) wT[wv] = vS;
    __syncthreads();
    double add = 0.0;
    for (int w2 = wv + 1; w2 < 8; ++w2) add += wT[w2];
    double Si = vS + add;
    double baseS = R.Sbef4, t4d = (double)R.t4;
    if (c){
      if (baseS + Si >= t4d) atomicMax(&mx, t);
      atomicMin(&mnz, t);
    }
    __syncthreads();
    int w = (mx >= 0) ? mx : ((mnz < NB2) ? mnz : -1);
    if (w < 0){
      if (t) return;
      token = R.i0; pB = R.v0;
    } else {
      if (t == w) sSbS = baseS + (Si - s);
      __syncthreads();
      for (int j = t; j < n; j += WTPB){
        unsigned long long e = q4big[(size_t)b*CAPB + j];
        unsigned K = ~(unsigned)(e >> 32);
        if (((K >> 12) & (NB2-1)) == (unsigned)w){
          int p = atomicAdd(&mcnt, 1);
          if (p < CAP) Ls[p] = e;
        }
      }
      __syncthreads();
      if (t) return;
      int m = mcnt; if (m > CAP) m = CAP;
      for (int i2 = 1; i2 < m; ++i2){
        unsigned long long key = Ls[i2]; int j = i2-1;
        while (j >= 0 && Ls[j] > key){ Ls[j+1] = Ls[j]; --j; }
        Ls[j+1] = key;
      }
      double S = sSbS, t4dd = (double)R.t4;
      unsigned v0 = R.v0; int i0 = R.i0;
      token = -1; pB = R.v0;
      for (int j = 0; j < m; ++j){
        unsigned K = ~(unsigned)(Ls[j] >> 32);
        int idx = (int)(unsigned)(Ls[j] & 0xFFFFFFFFu);
        bool kept = (K > v0) || (K == v0 && idx <= i0);
        if (!kept){ token = i0; pB = v0; break; }
        S += (double)__uint_as_float(K);
        if (S >= t4dd){ token = idx; pB = K; break; }
      }
      if (token < 0){ token = i0; pB = v0; }
    }
  }
  unsigned v2 = R.v2; int i2 = R.i2;
  bool kept2 = (pB > v2) || (pB == v2 && token <= i2);
  float pt = __uint_as_float(pB);
  float lp = kept2 ? fmaxf(logf(pt) - logf(R.S2f), FMINV) : FOUT;
  outTok[b] = (float)token;
  outNtlp[b] = lp;
}

extern "C" void kernel_launch(void* const* d_in, const int* in_sizes, int n_in,
                              void* d_out, int out_size, void* d_ws, size_t ws_size,
                              hipStream_t stream)
{
  const float* logits  = (const float*)d_in[0];
  const float* temps   = (const float*)d_in[1];
  const int*   top_ks  = (const int*)d_in[2];
  const float* top_ps  = (const float*)d_in[3];
  const float* top_ps2 = (const float*)d_in[4];
  const float* min_ps  = (const float*)d_in[5];
  const float* uarr    = (const float*)d_in[6];

  char* ws = (char*)d_ws;
  RowWS*    rows   = (RowWS*)(ws + OFF_ROWS);
  float*    sliceM = (float*)(ws + OFF_SLICEM);
  unsigned long long* L1P   = (unsigned long long*)(ws + OFF_L1P);
  unsigned* lcnt   = (unsigned*)(ws + OFF_LCNT);
  unsigned long long* lists = (unsigned long long*)(ws + OFF_LISTS);
  unsigned long long* q4big = (unsigned long long*)(ws + OFF_Q4BIG);

  float* outTok  = (float*)d_out;
  float* outLp   = outTok + Bn;
  float* outNtlp = outLp + (size_t)Bn * Vn;
  unsigned* Kc   = (unsigned*)outLp;     // K-cache lives in the big output buffer

  const int G = Bn * SLICES;
  hipMemsetAsync(ws + ZERO_BEG, 0, ZERO_BYTES, stream);
  k_max      <<<G,  TPB,  0, stream>>>(logits, sliceM);
  k_l1hist   <<<G,  TPB,  0, stream>>>(logits, temps, sliceM, L1P, Kc);
  k_collectB <<<G,  TPB,  0, stream>>>(Kc, L1P, rows, top_ks, top_ps, top_ps2, min_ps, lists, lcnt);
  k_resolve2 <<<Bn, WTPB, 0, stream>>>(rows, lists, lcnt, L1P, top_ks, top_ps, top_ps2, uarr);
  k_out2     <<<G,  TPB,  0, stream>>>(rows, q4big, lcnt, outLp);
  k_pick2    <<<Bn, WTPB, 0, stream>>>(rows, q4big, lcnt, outTok, outNtlp);
}